// Round 8
// baseline (814.732 us; speedup 1.0000x reference)
//
#include <hip/hip_runtime.h>
#include <hip/hip_bf16.h>
#include <stdint.h>

#define U_N   100000
#define I_N   200000
#define NN    300000
#define DD    64
#define NNZ_N 6400000
#define BB    4096
#define RPB   1024                         // rows per bucket
#define NBK   293                          // ceil(NN/RPB) coarse buckets
#define EPB   4096                         // edges per pass-1 block
#define BKCAP 25088                        // fixed bucket capacity (mean 21843, +22 sigma)
#define LBLK  48000                        // spmm_list grid: 192000 slots >= nlist
#define P1B   ((NNZ_N + EPB - 1) / EPB)    // 1563 p1 blocks
#define PACKB ((NN * 16) / 256)            // 18750 pack blocks
#define ACCB  ((2 * BB * 32) / 256)        // 1024 init_acc blocks

typedef unsigned short u16;
typedef unsigned int   u32;
typedef float vf2 __attribute__((ext_vector_type(2)));

__device__ __forceinline__ u16 f2bf(float f) {
    u32 u = __float_as_uint(f);
    u32 r = (u + 0x7FFFu + ((u >> 16) & 1u)) >> 16;
    return (u16)r;
}

// ---------------- fp8 e4m3fn encode/decode (OCP; HW converts on gfx950) ----------------

#if __has_builtin(__builtin_amdgcn_cvt_pk_f32_fp8) && __has_builtin(__builtin_amdgcn_cvt_pk_fp8_f32)
#define FP8_HW 1
#else
#define FP8_HW 0
#endif

__device__ __forceinline__ u32 enc1_fp8(float f) {
    float af = fabsf(f);
    u32 s = (__float_as_uint(f) >> 31) << 7;
    if (af >= 0.015625f) {
        u32 au = __float_as_uint(af);
        u32 r = au + 0x7FFFFu + ((au >> 20) & 1u);
        u32 e = (r >> 23) - 120u;
        u32 m = (r >> 20) & 7u;
        if (e > 15u) { e = 15u; m = 6u; }
        return s | (e << 3) | m;
    } else {
        u32 q = (u32)__float2int_rn(af * 512.0f);   // RNE into subnormal grid 2^-9
        return s | q;
    }
}

__device__ __forceinline__ u32 pack4_fp8(float a, float b, float c, float d) {
#if FP8_HW
    u32 w = 0;
    w = (u32)__builtin_amdgcn_cvt_pk_fp8_f32(a, b, (int)w, false);
    w = (u32)__builtin_amdgcn_cvt_pk_fp8_f32(c, d, (int)w, true);
    return w;
#else
    return enc1_fp8(a) | (enc1_fp8(b) << 8) | (enc1_fp8(c) << 16) | (enc1_fp8(d) << 24);
#endif
}

__device__ __forceinline__ float dec1_fp8(u32 b) {
    u32 s = (b & 0x80u) << 24;
    u32 e = (b >> 3) & 15u;
    u32 m = b & 7u;
    float mag = e ? __uint_as_float(((e + 120u) << 23) | (m << 20))
                  : (float)m * 0.001953125f;   // 2^-9
    return __uint_as_float(__float_as_uint(mag) | s);
}

__device__ __forceinline__ void dec_fp8x4(u32 w, float* f) {
#if FP8_HW
    vf2 lo = __builtin_amdgcn_cvt_pk_f32_fp8((int)w, false);
    vf2 hi = __builtin_amdgcn_cvt_pk_f32_fp8((int)w, true);
    f[0] = lo[0]; f[1] = lo[1]; f[2] = hi[0]; f[3] = hi[1];
#else
    f[0] = dec1_fp8(w & 255u); f[1] = dec1_fp8((w >> 8) & 255u);
    f[2] = dec1_fp8((w >> 16) & 255u); f[3] = dec1_fp8(w >> 24);
#endif
}

// ---------------- setup: zero mark/bmark/nlist + bucket cursor init --------

__global__ void setup_k(unsigned char* __restrict__ mark, unsigned char* __restrict__ bmark,
                        int* __restrict__ nlist, int* __restrict__ bkt_cursor) {
    int tid = blockIdx.x * 256 + threadIdx.x;
    if (tid < NN / 4) { ((u32*)mark)[tid] = 0; ((u32*)bmark)[tid] = 0; }
    if (tid < NBK) bkt_cursor[tid] = tid * BKCAP;
    if (tid == NN / 4) nlist[0] = 0;
}

// ---------------- fused1: p1 bucket scatter + pack1 fp8 + init_acc ----------------
// payload: pk = (row&1023)<<19 | col  (row_local 10b + col 19b); bucket = row>>10.
// scatters to fixed region [b*BKCAP, b*BKCAP + cnt_b).

__global__ __launch_bounds__(256) void fused1_k(const int* __restrict__ adj_row,
                                                const int* __restrict__ adj_col,
                                                const float* __restrict__ adj_val,
                                                int* __restrict__ bkt_cursor,
                                                u32* __restrict__ bpk,
                                                float* __restrict__ bval,
                                                const float* __restrict__ ue_on,
                                                const float* __restrict__ ie_on,
                                                const float* __restrict__ ue_tg,
                                                const float* __restrict__ ie_tg,
                                                unsigned char* __restrict__ x0f,
                                                const int* __restrict__ user_idx,
                                                const int* __restrict__ item_idx,
                                                float* __restrict__ out_acc) {
    __shared__ int lcnt[NBK];
    __shared__ int lbase[NBK];
    int bid = blockIdx.x;
    if (bid < P1B) {
        // ---- p1 body ----
        int base = bid * EPB;
        for (int i = threadIdx.x; i < NBK; i += 256) lcnt[i] = 0;
        __syncthreads();
        u32 pk[16]; float vv[16]; int bb[16]; int rk[16];
#pragma unroll
        for (int j = 0; j < 16; j++) {
            int e = base + j * 256 + threadIdx.x;
            bb[j] = -1;
            if (e < NNZ_N) {
                int r = adj_row[e];
                int c = adj_col[e];
                vv[j] = adj_val[e];
                int b = r >> 10;
                pk[j] = ((u32)(r & 1023) << 19) | (u32)c;
                bb[j] = b;
                rk[j] = atomicAdd(&lcnt[b], 1);
            }
        }
        __syncthreads();
        for (int i = threadIdx.x; i < NBK; i += 256)
            lbase[i] = atomicAdd(&bkt_cursor[i], lcnt[i]);
        __syncthreads();
#pragma unroll
        for (int j = 0; j < 16; j++) {
            if (bb[j] >= 0) {
                int p = lbase[bb[j]] + rk[j];
                bpk[p]  = pk[j];
                bval[p] = vv[j];
            }
        }
        return;
    }
    bid -= P1B;
    if (bid < PACKB) {
        // ---- pack1 body: x0 as fp8 e4m3fn [N,128] ----
        int tid = bid * 256 + threadIdx.x;   // NN*16 threads
        int n = tid >> 4;
        int t = tid & 15;
        if (n >= NN) return;
        const float* src;
        int soff;
        if (t < 8) {
            soff = t * 8;
            src = (n < U_N) ? ue_on + (size_t)n * 64 : ie_on + (size_t)(n - U_N) * 64;
        } else {
            soff = (t - 8) * 8;
            src = (n < U_N) ? ue_tg + (size_t)n * 64 : ie_tg + (size_t)(n - U_N) * 64;
        }
        float4 f0 = *(const float4*)(src + soff);
        float4 f1 = *(const float4*)(src + soff + 4);
        uint2 o;
        o.x = pack4_fp8(f0.x, f0.y, f0.z, f0.w);
        o.y = pack4_fp8(f1.x, f1.y, f1.z, f1.w);
        *(uint2*)(x0f + (size_t)n * 128 + t * 8) = o;
        return;
    }
    bid -= PACKB;
    {
        // ---- init_acc body ----
        int t = bid * 256 + threadIdx.x;   // 2B*32 threads
        int slot = t >> 5;
        int j = t & 31;
        if (slot >= 2 * BB) return;
        int node = (slot < BB) ? user_idx[slot] : U_N + item_idx[slot - BB];
        const float* src;
        int soff, doff;
        if (j < 16) {
            soff = j * 4; doff = j * 4;
            src = (node < U_N) ? ue_on + (size_t)node * 64 : ie_on + (size_t)(node - U_N) * 64;
        } else {
            soff = (j - 16) * 4; doff = 64 + (j - 16) * 4;
            src = (node < U_N) ? ue_tg + (size_t)node * 64 : ie_tg + (size_t)(node - U_N) * 64;
        }
        float4 f = *(const float4*)(src + soff);
        *(float4*)(out_acc + (size_t)slot * 128 + doff) = f;
    }
}

// ---------------- bsort: one block per bucket -> row_ptr + final row-sorted edge_s ----
// Replaces {bhist, scan1/2/3, p2r, p3, sub_cursor}: (a) LDS histogram of the
// bucket's 1024 rows, (b) in-block scans (cross-bucket totals re-derived from
// bkt_cursor by every block -- 293 values, trivial), write row_ptr, (c) re-read
// edges and scatter straight to final edge_s position via LDS row cursors.
// Writes land in a dense ~175KB window per bucket -> L2-absorbed.

__global__ __launch_bounds__(1024) void bsort_k(const int* __restrict__ bkt_cursor,
                                                const u32* __restrict__ bpk,
                                                const float* __restrict__ bval,
                                                int2* __restrict__ edge_s,
                                                int* __restrict__ row_ptr) {
    __shared__ int h[RPB];     // per-row histogram -> cursor
    __shared__ int bs[512];    // bucket-total scan
    int b = blockIdx.x;
    int t = threadIdx.x;
    int base = b * BKCAP;
    int e1 = bkt_cursor[b];                  // base + cnt_b after p1
    // cross-bucket totals (every block computes the same 512-wide scan)
    int v = 0;
    if (t < 512) {
        v = (t < NBK) ? bkt_cursor[t] - t * BKCAP : 0;
        bs[t] = v;
    }
    h[t] = 0;
    __syncthreads();
    for (int o = 1; o < 512; o <<= 1) {
        int tmp = 0;
        if (t < 512 && t >= o) tmp = bs[t - o];
        __syncthreads();
        if (t < 512) bs[t] += tmp;
        __syncthreads();
    }
    int bucket_base = (b == 0) ? 0 : bs[b - 1];   // exclusive prefix (bs now inclusive)
    if (b == NBK - 1 && t == 0) row_ptr[NN] = bs[NBK - 1];   // total = NNZ
    // (a) histogram
    for (int i = base + t; i < e1; i += 1024)
        atomicAdd(&h[bpk[i] >> 19], 1);
    __syncthreads();
    // (b) in-block exclusive scan of h -> row start offsets
    int hv = h[t];
    for (int o = 1; o < 1024; o <<= 1) {
        int tmp = (t >= o) ? h[t - o] : 0;
        __syncthreads();
        h[t] += tmp;
        __syncthreads();
    }
    int excl = h[t] - hv;
    int r = b * RPB + t;
    if (r < NN) row_ptr[r] = bucket_base + excl;
    __syncthreads();
    h[t] = bucket_base + excl;               // global running cursor
    __syncthreads();
    // (c) scatter to final positions
    for (int i = base + t; i < e1; i += 1024) {
        u32 pk = bpk[i];
        float vv = bval[i];
        int l = (int)(pk >> 19);
        int pos = atomicAdd(&h[l], 1);
        edge_s[pos] = make_int2((int)(pk & 0x7FFFFu), __float_as_int(vv));
    }
}

// ---------------- frontier: rows actually needed for layer 2 ----------------
// also sets bmark = batch-node flag (restricts spmm1's bf16 output to 8192 rows)

__global__ void mark_k(const int* __restrict__ row_ptr, const int2* __restrict__ edge_s,
                       const int* __restrict__ user_idx, const int* __restrict__ item_idx,
                       unsigned char* __restrict__ mark, unsigned char* __restrict__ bmark) {
    int wave = threadIdx.x >> 6;
    int lane = threadIdx.x & 63;
    int slot = blockIdx.x * 4 + wave;
    if (slot >= 2 * BB) return;
    int r = (slot < BB) ? user_idx[slot] : U_N + item_idx[slot - BB];
    if (lane == 0) { mark[r] = 1; bmark[r] = 1; }
    int e0 = row_ptr[r], e1 = row_ptr[r + 1];
    for (int e = e0 + lane; e < e1; e += 64) mark[edge_s[e].x] = 1;
}

__global__ void compact_k(const unsigned char* __restrict__ mark,
                          int* __restrict__ list2, int* __restrict__ nlist) {
    int i = blockIdx.x * 256 + threadIdx.x;
    int lane = threadIdx.x & 63;
    int m = (i < NN) ? (int)mark[i] : 0;
    unsigned long long b = __ballot(m != 0);
    int pre = __popcll(b & ((1ull << lane) - 1ull));
    int tot = __popcll(b);
    int base = 0;
    if (lane == 0 && tot) base = atomicAdd(nlist, tot);
    base = __shfl(base, 0);
    if (m) list2[base + pre] = i;
}

// ---------------- SpMM cores: wave = 1 row, 4 subgroups x 16 lanes ----------------
// Batched-MLP: issue 8 independent edge loads, then 8 independent row gathers
// (masked slots zeroed), THEN decode. R3/R5 lessons: do NOT touch this loop's
// load forms (plain int2 loads, 1 row/wave) -- VGPR 36 / occupancy 72% is the
// proven sweet spot; nt intrinsics or 2-row batching both cost >20% via occupancy.

struct acc8 { float a[8]; };

__device__ __forceinline__ void red8(acc8& A) {
#pragma unroll
    for (int k = 0; k < 8; k++) {
        A.a[k] += __shfl_xor(A.a[k], 16);
        A.a[k] += __shfl_xor(A.a[k], 32);
    }
}

// fp8-input core (layer 1 and layer 2): 128B = one cache line per edge gather
__device__ __forceinline__ void rg8_core(const int2* __restrict__ edge_s,
                                         const unsigned char* __restrict__ xf,
                                         int t, int g, int e0, int e1, acc8& A) {
#pragma unroll
    for (int k = 0; k < 8; k++) A.a[k] = 0.f;
    const unsigned char* xt = xf + t * 8;
    int d = e1 - e0;

    int2 ed[8];
    uint2 pv[8];
#pragma unroll
    for (int q = 0; q < 8; q++) { ed[q] = make_int2(0, 0); pv[q] = make_uint2(0u, 0u); }
#pragma unroll
    for (int q = 0; q < 8; q++) {
        int j = g + 4 * q;
        if (j < d) ed[q] = edge_s[e0 + j];
    }
#pragma unroll
    for (int q = 0; q < 8; q++) {
        int j = g + 4 * q;
        if (j < d) pv[q] = *(const uint2*)(xt + (size_t)((u32)ed[q].x * 128u));
    }
#pragma unroll
    for (int q = 0; q < 8; q++) {
        float v = __int_as_float(ed[q].y);   // 0.0f for masked slots
        float f[8];
        dec_fp8x4(pv[q].x, f);
        dec_fp8x4(pv[q].y, f + 4);
#pragma unroll
        for (int k = 0; k < 8; k++) A.a[k] += v * f[k];
    }
    // tail: edges 32..d-1 (deg ~ Poisson(21.3), rare)
    for (int e = e0 + 32 + g * 4; e < e1; e += 16) {
        int m = e1 - e;   // subgroup-uniform
#pragma unroll
        for (int k = 0; k < 4; k++) {
            if (k < m) {
                int2 dd = edge_s[e + k];
                float v = __int_as_float(dd.y);
                uint2 p = *(const uint2*)(xt + (size_t)((u32)dd.x * 128u));
                float f[8];
                dec_fp8x4(p.x, f);
                dec_fp8x4(p.y, f + 4);
#pragma unroll
                for (int q = 0; q < 8; q++) A.a[q] += v * f[q];
            }
        }
    }
    red8(A);
}

// layer 1: full graph; writes fp8 x1 mirror for ALL rows (gather source for layer 2)
// and bf16 x1 ONLY for batch rows (gadd reads just those 8192 -> 97% write cut).
// The gate lives in the epilogue (after red8): no effect on loop VGPR watermark.
__global__ __launch_bounds__(256) void spmm1_k(const int* __restrict__ row_ptr,
                                               const int2* __restrict__ edge_s,
                                               const unsigned char* __restrict__ x0f,
                                               const unsigned char* __restrict__ bmark,
                                               u16* __restrict__ y,
                                               unsigned char* __restrict__ yf) {
    int lane = threadIdx.x & 63;
    int t = lane & 15, g = lane >> 4;
    int r = blockIdx.x * 4 + (threadIdx.x >> 6);
    if (r >= NN) return;
    acc8 A;
    rg8_core(edge_s, x0f, t, g, row_ptr[r], row_ptr[r + 1], A);
    if (g == 0) {
        uint2 of;
        of.x = pack4_fp8(A.a[0], A.a[1], A.a[2], A.a[3]);
        of.y = pack4_fp8(A.a[4], A.a[5], A.a[6], A.a[7]);
        *(uint2*)(yf + (size_t)r * 128 + t * 8) = of;
        if (bmark[r]) {
            uint4 o;
            o.x = ((u32)f2bf(A.a[1]) << 16) | (u32)f2bf(A.a[0]);
            o.y = ((u32)f2bf(A.a[3]) << 16) | (u32)f2bf(A.a[2]);
            o.z = ((u32)f2bf(A.a[5]) << 16) | (u32)f2bf(A.a[4]);
            o.w = ((u32)f2bf(A.a[7]) << 16) | (u32)f2bf(A.a[6]);
            *(uint4*)(y + (size_t)r * 128 + t * 8) = o;
        }
    }
}

// bf16-input core (layer 3)
__device__ __forceinline__ void rg16_core(const int2* __restrict__ edge_s,
                                          const u16* __restrict__ x,
                                          int t, int g, int e0, int e1, acc8& A) {
#pragma unroll
    for (int k = 0; k < 8; k++) A.a[k] = 0.f;
    const u16* xt = x + t * 8;
    int d = e1 - e0;

    int2 ed[8];
    uint4 pv[8];
#pragma unroll
    for (int q = 0; q < 8; q++) { ed[q] = make_int2(0, 0); pv[q] = make_uint4(0u, 0u, 0u, 0u); }
#pragma unroll
    for (int q = 0; q < 8; q++) {
        int j = g + 4 * q;
        if (j < d) ed[q] = edge_s[e0 + j];
    }
#pragma unroll
    for (int q = 0; q < 8; q++) {
        int j = g + 4 * q;
        if (j < d) pv[q] = *(const uint4*)(xt + (size_t)(u32)ed[q].x * 128);
    }
#pragma unroll
    for (int q = 0; q < 8; q++) {
        float v = __int_as_float(ed[q].y);   // 0.0f for masked slots
        A.a[0] += v * __uint_as_float(pv[q].x << 16);
        A.a[1] += v * __uint_as_float(pv[q].x & 0xFFFF0000u);
        A.a[2] += v * __uint_as_float(pv[q].y << 16);
        A.a[3] += v * __uint_as_float(pv[q].y & 0xFFFF0000u);
        A.a[4] += v * __uint_as_float(pv[q].z << 16);
        A.a[5] += v * __uint_as_float(pv[q].z & 0xFFFF0000u);
        A.a[6] += v * __uint_as_float(pv[q].w << 16);
        A.a[7] += v * __uint_as_float(pv[q].w & 0xFFFF0000u);
    }
    // tail: edges 32..d-1
    for (int e = e0 + 32 + g * 4; e < e1; e += 16) {
        int m = e1 - e;
#pragma unroll
        for (int k = 0; k < 4; k++) {
            if (k < m) {
                int2 dd = edge_s[e + k];
                float v = __int_as_float(dd.y);
                uint4 p = *(const uint4*)(xt + (size_t)(u32)dd.x * 128);
                A.a[0] += v * __uint_as_float(p.x << 16);
                A.a[1] += v * __uint_as_float(p.x & 0xFFFF0000u);
                A.a[2] += v * __uint_as_float(p.y << 16);
                A.a[3] += v * __uint_as_float(p.y & 0xFFFF0000u);
                A.a[4] += v * __uint_as_float(p.z << 16);
                A.a[5] += v * __uint_as_float(p.z & 0xFFFF0000u);
                A.a[6] += v * __uint_as_float(p.w << 16);
                A.a[7] += v * __uint_as_float(p.w & 0xFFFF0000u);
            }
        }
    }
    red8(A);
}

// layer 2: frontier rows only; gathers fp8 x1 mirror, writes bf16 x2
__global__ __launch_bounds__(256) void spmm_list_k(const int* __restrict__ row_ptr,
                                                   const int2* __restrict__ edge_s,
                                                   const unsigned char* __restrict__ x1f,
                                                   u16* __restrict__ y,
                                                   const int* __restrict__ list2,
                                                   const int* __restrict__ nlist) {
    int lane = threadIdx.x & 63;
    int t = lane & 15, g = lane >> 4;
    int slot = blockIdx.x * 4 + (threadIdx.x >> 6);
    if (slot >= *nlist) return;
    int r = list2[slot];
    acc8 A;
    rg8_core(edge_s, x1f, t, g, row_ptr[r], row_ptr[r + 1], A);
    if (g == 0) {
        uint4 o;
        o.x = ((u32)f2bf(A.a[1]) << 16) | (u32)f2bf(A.a[0]);
        o.y = ((u32)f2bf(A.a[3]) << 16) | (u32)f2bf(A.a[2]);
        o.z = ((u32)f2bf(A.a[5]) << 16) | (u32)f2bf(A.a[4]);
        o.w = ((u32)f2bf(A.a[7]) << 16) | (u32)f2bf(A.a[6]);
        *(uint4*)(y + (size_t)r * 128 + t * 8) = o;
    }
}

// last layer: only the 8192 batch rows, fp32 accumulate into out_acc.
// gadd for x2 fused into the epilogue (adds bf16 x2[node] before the RMW).
__global__ __launch_bounds__(256) void spmm_last_k(const int* __restrict__ row_ptr,
                                                   const int2* __restrict__ edge_s,
                                                   const u16* __restrict__ x,
                                                   const int* __restrict__ user_idx,
                                                   const int* __restrict__ item_idx,
                                                   float* __restrict__ out_acc) {
    int lane = threadIdx.x & 63;
    int t = lane & 15, g = lane >> 4;
    int slot = blockIdx.x * 4 + (threadIdx.x >> 6);
    if (slot >= 2 * BB) return;
    int r = (slot < BB) ? user_idx[slot] : U_N + item_idx[slot - BB];
    acc8 A;
    rg16_core(edge_s, x, t, g, row_ptr[r], row_ptr[r + 1], A);
    if (g == 0) {
        // fused gadd: add x2[r] (bf16) into the layer-3 sums
        uint4 p = *(const uint4*)(x + (size_t)r * 128 + t * 8);
        A.a[0] += __uint_as_float(p.x << 16);
        A.a[1] += __uint_as_float(p.x & 0xFFFF0000u);
        A.a[2] += __uint_as_float(p.y << 16);
        A.a[3] += __uint_as_float(p.y & 0xFFFF0000u);
        A.a[4] += __uint_as_float(p.z << 16);
        A.a[5] += __uint_as_float(p.z & 0xFFFF0000u);
        A.a[6] += __uint_as_float(p.w << 16);
        A.a[7] += __uint_as_float(p.w & 0xFFFF0000u);
        float4* p0 = (float4*)(out_acc + (size_t)slot * 128 + t * 8);
        float4 c0 = p0[0], c1 = p0[1];
        c0.x += A.a[0]; c0.y += A.a[1]; c0.z += A.a[2]; c0.w += A.a[3];
        c1.x += A.a[4]; c1.y += A.a[5]; c1.z += A.a[6]; c1.w += A.a[7];
        p0[0] = c0; p0[1] = c1;
    }
}

// ---------------- gadd: add bf16 x1[node] into out_acc (batch rows) ----------------

__global__ void gadd_k(const int* __restrict__ user_idx, const int* __restrict__ item_idx,
                       const u16* __restrict__ x, float* __restrict__ out_acc) {
    int t = blockIdx.x * blockDim.x + threadIdx.x;   // 2B*64 threads
    int slot = t >> 6;
    int l = t & 63;
    if (slot >= 2 * BB) return;
    int node = (slot < BB) ? user_idx[slot] : U_N + item_idx[slot - BB];
    u32 p = *(const u32*)(x + (size_t)node * 128 + (l << 1));
    float fx = __uint_as_float(p << 16);
    float fy = __uint_as_float(p & 0xFFFF0000u);
    float2* q = (float2*)(out_acc + (size_t)slot * 128) + l;
    float2 cur = *q;
    cur.x += fx; cur.y += fy;
    *q = cur;
}

// ---------------- epilogue: preds (GEMM) + targets fused ----------------

__global__ __launch_bounds__(256) void pred_k(const float* __restrict__ out_acc,
                                              const float* __restrict__ W,
                                              const float* __restrict__ bias,
                                              float* __restrict__ out) {
    __shared__ float wld[64 * 65];   // W transposed, padded
    __shared__ float uld[4 * 64];
    int j = threadIdx.x & 63;
    int rl = threadIdx.x >> 6;
    for (int i = threadIdx.x; i < 4096; i += 256) {
        int jj = i >> 6, kk = i & 63;
        wld[kk * 65 + jj] = W[i];
    }
    int slot = blockIdx.x * 4 + rl;
    uld[rl * 64 + j] = out_acc[(size_t)slot * 128 + j] * 0.25f;
    // target: cols 64..127, scaled
    float tv = out_acc[(size_t)slot * 128 + 64 + j] * 0.25f;
    size_t tdst = (slot < BB) ? (size_t)BB * 64 + (size_t)slot * 64 + j
                              : (size_t)3 * BB * 64 + (size_t)(slot - BB) * 64 + j;
    out[tdst] = tv;
    __syncthreads();
    float acc = bias[j];
#pragma unroll
    for (int k = 0; k < 64; k++) acc += uld[rl * 64 + k] * wld[k * 65 + j];
    size_t dst = (slot < BB) ? (size_t)slot * 64 + j
                             : (size_t)2 * BB * 64 + (size_t)(slot - BB) * 64 + j;
    out[dst] = acc;
}

// ---------------- launch ----------------

extern "C" void kernel_launch(void* const* d_in, const int* in_sizes, int n_in,
                              void* d_out, int out_size, void* d_ws, size_t ws_size,
                              hipStream_t stream) {
    const float* ue_on = (const float*)d_in[0];
    const float* ie_on = (const float*)d_in[1];
    const float* ue_tg = (const float*)d_in[2];
    const float* ie_tg = (const float*)d_in[3];
    const float* adj_val = (const float*)d_in[4];
    const float* pred_w = (const float*)d_in[5];
    const float* pred_b = (const float*)d_in[6];
    const int* adj_row = (const int*)d_in[7];
    const int* adj_col = (const int*)d_in[8];
    const int* user_idx = (const int*)d_in[9];
    const int* item_idx = (const int*)d_in[10];
    float* out = (float*)d_out;

    char* ws = (char*)d_ws;
    size_t off = 0;
    auto alloc = [&](size_t bytes) -> char* {
        char* p = ws + off;
        off = (off + bytes + 255) & ~(size_t)255;
        return p;
    };
    int*   row_ptr    = (int*)alloc((size_t)(NN + 1) * 4);
    int*   bkt_cursor = (int*)alloc(512 * 4);
    unsigned char* mark = (unsigned char*)alloc((size_t)NN);
    unsigned char* bmark = (unsigned char*)alloc((size_t)NN);
    int*   list2      = (int*)alloc((size_t)NN * 4);
    int*   nlist      = (int*)alloc(256 * 4);
    int2*  edge_s     = (int2*)alloc((size_t)NNZ_N * 8);
    u16*   x_a        = (u16*)alloc((size_t)NN * 128 * 2);
    u16*   x_b        = (u16*)alloc((size_t)NN * 128 * 2);
    float* out_acc    = (float*)alloc((size_t)2 * BB * 128 * 4);

    // aliases (all consumed before their underlying role begins):
    //   x0f  -> x_a [0, 38.4MB)       (pack1 in fused1; dead after spmm1)
    //   x1f  -> x_a [38.4, 76.8MB)    fp8 mirror of x1 (spmm1 -> spmm_list)
    //   bval -> x_b [0, 29.4MB)       (dead after bsort)
    //   bpk  -> x_b [38.4, 67.8MB)    (dead after bsort; both precede x_b's bf16
    //                                  roles: x1 batch rows (spmm1 -> gadd), then
    //                                  x2 frontier rows (spmm_list -> spmm_last))
    unsigned char* x0f = (unsigned char*)x_a;
    unsigned char* x1f = (unsigned char*)x_a + (size_t)NN * 128;
    float* bval = (float*)x_b;
    u32*   bpk  = (u32*)((char*)x_b + (size_t)NN * 128);

    (void)n_in; (void)in_sizes; (void)out_size; (void)ws_size;

    // 1. setup, then fused {CSR bucket scatter + fp8 pack + acc init}
    setup_k<<<294, 256, 0, stream>>>(mark, bmark, nlist, bkt_cursor);
    fused1_k<<<P1B + PACKB + ACCB, 256, 0, stream>>>(adj_row, adj_col, adj_val,
                                                     bkt_cursor, bpk, bval,
                                                     ue_on, ie_on, ue_tg, ie_tg, x0f,
                                                     user_idx, item_idx, out_acc);
    // 2. single-pass bucket sort: row_ptr + row-sorted edge_s
    bsort_k<<<NBK, 1024, 0, stream>>>(bkt_cursor, bpk, bval, edge_s, row_ptr);

    // 3. frontier for layer-2 restriction + batch-node flags
    mark_k<<<(2 * BB) / 4, 256, 0, stream>>>(row_ptr, edge_s, user_idx, item_idx, mark, bmark);
    compact_k<<<(NN + 255) / 256, 256, 0, stream>>>(mark, list2, nlist);

    // 4. layer 1 (full, fp8 gathers, dual output), gadd x1, layer 2 (frontier, fp8),
    //    layer 3 (batch rows + fused gadd x2)
    spmm1_k<<<NN / 4, 256, 0, stream>>>(row_ptr, edge_s, x0f, bmark, x_b, x1f);
    gadd_k<<<(2 * BB * 64) / 256, 256, 0, stream>>>(user_idx, item_idx, x_b, out_acc);
    spmm_list_k<<<LBLK, 256, 0, stream>>>(row_ptr, edge_s, x1f, x_b, list2, nlist);
    spmm_last_k<<<(2 * BB) / 4, 256, 0, stream>>>(row_ptr, edge_s, x_b, user_idx, item_idx, out_acc);

    // 5. epilogue (preds + targets fused)
    pred_k<<<(2 * BB) / 4, 256, 0, stream>>>(out_acc, pred_w, pred_b, out);
}